// Round 2
// baseline (292.008 us; speedup 1.0000x reference)
//
#include <hip/hip_runtime.h>
#include <math.h>

// Shapes (fixed by the reference)
#define BB   16
#define CC   16      // IN_CHAN
#define LL   4096
#define OUTC 64
#define KS   7

typedef float vfloat4 __attribute__((ext_vector_type(4)));

__global__ __launch_bounds__(256) void deform_conv_kernel(
    const float* __restrict__ x,    // (B,1,L,C) -> x[(b*L + l)*C + c]
    const float* __restrict__ p_w,  // (7,1,3)
    const float* __restrict__ p_b,  // (7,)
    const float* __restrict__ m_w,  // (7,1,3)
    const float* __restrict__ m_b,  // (7,)
    const float* __restrict__ c_w,  // (64,1,7)
    const float* __restrict__ c_b,  // (64,)
    float* __restrict__ out)        // (B,64,L,C)
{
    __shared__ float cw_lds[OUTC * 8];  // [o][0..6]=w, [7]=bias
    __shared__ float pw_lds[KS * 4];    // [k][0..2]=w, [3]=bias
    __shared__ float mw_lds[KS * 4];

    const int tid = threadIdx.x;

    // Stage weights into LDS (broadcast reads later are conflict-free)
    for (int i = tid; i < OUTC * 8; i += 256) {
        int o = i >> 3, j = i & 7;
        cw_lds[i] = (j < 7) ? c_w[o * 7 + j] : c_b[o];
    }
    if (tid < KS * 4) {
        int k = tid >> 2, j = tid & 3;
        pw_lds[tid] = (j < 3) ? p_w[k * 3 + j] : p_b[k];
        mw_lds[tid] = (j < 3) ? m_w[k * 3 + j] : m_b[k];
    }
    __syncthreads();

    const int b     = blockIdx.x >> 6;   // 16 batches
    const int ltile = blockIdx.x & 63;   // 64 tiles of 64 positions
    const int cg    = tid & 3;           // channel quad: c0 = cg*4
    const int l     = ltile * 64 + (tid >> 2);
    const int c0    = cg * 4;

    const float* xb = x + b * (LL * CC);  // xb[l*CC + c] == sig[c][l]

    // 3-tap conv inputs (zero pad at boundaries)
    float s_m1[4] = {0.f, 0.f, 0.f, 0.f};
    float s_p1[4] = {0.f, 0.f, 0.f, 0.f};
    float s_0[4];
    {
        float4 v0 = *(const float4*)(xb + l * CC + c0);
        s_0[0] = v0.x; s_0[1] = v0.y; s_0[2] = v0.z; s_0[3] = v0.w;
        if (l > 0) {
            float4 vm = *(const float4*)(xb + (l - 1) * CC + c0);
            s_m1[0] = vm.x; s_m1[1] = vm.y; s_m1[2] = vm.z; s_m1[3] = vm.w;
        }
        if (l < LL - 1) {
            float4 vp = *(const float4*)(xb + (l + 1) * CC + c0);
            s_p1[0] = vp.x; s_p1[1] = vp.y; s_p1[2] = vp.z; s_p1[3] = vp.w;
        }
    }

    // Compute x_off[c][k] (bilinear-gathered, masked samples)
    float xoff[4][KS];
    const float pl = (float)(l + 1);
    #pragma unroll
    for (int k = 0; k < KS; ++k) {
        float4 pw = *(const float4*)(pw_lds + k * 4);  // x,y,z = taps, w = bias
        float4 mw = *(const float4*)(mw_lds + k * 4);
        const float pn = (float)(k - 3);
        #pragma unroll
        for (int c = 0; c < 4; ++c) {
            float off  = pw.w + pw.x * s_m1[c] + pw.y * s_0[c] + pw.z * s_p1[c];
            float mact = mw.w + mw.x * s_m1[c] + mw.y * s_0[c] + mw.z * s_p1[c];
            float mm   = 1.f / (1.f + __expf(-mact));   // sigmoid

            float p    = pl + pn + off;
            float qltf = fminf(fmaxf(floorf(p), 0.f), (float)(LL - 1));
            float qrbf = fminf(qltf + 1.f, (float)(LL - 1));
            float pc   = fminf(fmaxf(p, 0.f), (float)(LL - 1));
            float glt  = 1.f + (qltf - pc);
            float grb  = 1.f - (qrbf - pc);

            int ilt = (int)qltf;
            int irb = (int)qrbf;
            float xlt = xb[ilt * CC + c0 + c];   // local gather, L1/L2 hit
            float xrb = xb[irb * CC + c0 + c];

            xoff[c][k] = (glt * xlt + grb * xrb) * mm;
        }
    }

    // 7 -> 64 output-channel dot; float4 nontemporal stores (write-streaming)
    float* outp = out + ((size_t)(b * OUTC) * LL + l) * CC + c0;
    #pragma unroll 4
    for (int o = 0; o < OUTC; ++o) {
        float4 w0 = *(const float4*)(cw_lds + o * 8);      // k=0..3
        float4 w1 = *(const float4*)(cw_lds + o * 8 + 4);  // k=4..6, bias
        float acc[4];
        #pragma unroll
        for (int c = 0; c < 4; ++c) {
            float a = w1.w;
            a += w0.x * xoff[c][0];
            a += w0.y * xoff[c][1];
            a += w0.z * xoff[c][2];
            a += w0.w * xoff[c][3];
            a += w1.x * xoff[c][4];
            a += w1.y * xoff[c][5];
            a += w1.z * xoff[c][6];
            acc[c] = a;
        }
        vfloat4 res;
        res.x = acc[0]; res.y = acc[1]; res.z = acc[2]; res.w = acc[3];
        __builtin_nontemporal_store(res, (vfloat4*)(outp + (size_t)o * (LL * CC)));
    }
}

extern "C" void kernel_launch(void* const* d_in, const int* in_sizes, int n_in,
                              void* d_out, int out_size, void* d_ws, size_t ws_size,
                              hipStream_t stream) {
    const float* x   = (const float*)d_in[0];
    const float* p_w = (const float*)d_in[1];
    const float* p_b = (const float*)d_in[2];
    const float* m_w = (const float*)d_in[3];
    const float* m_b = (const float*)d_in[4];
    const float* c_w = (const float*)d_in[5];
    const float* c_b = (const float*)d_in[6];
    float* out = (float*)d_out;

    // grid: 16 batches x 64 l-tiles; block: 256 threads = 64 l x 4 channel-quads
    deform_conv_kernel<<<dim3(BB * 64), dim3(256), 0, stream>>>(
        x, p_w, p_b, m_w, m_b, c_w, c_b, out);
}